// Round 9
// baseline (860.736 us; speedup 1.0000x reference)
//
#include <hip/hip_runtime.h>
#include <hip/hip_bf16.h>
#include <hip/hip_cooperative_groups.h>
#include <cmath>

namespace cg = cooperative_groups;

// ---------------------------------------------------------------------------
// GAT 2-layer forward. 5 launches total:
//   1. k_csr (cooperative): weight prep + deg + scan + self-loops + 2-pass
//      dst-ranged scatter, grid.sync() between phases.
//   2. k_gemm1: LDS-free MFMA, fused scores1, int8 h1 + packed bf16 (score,scale).
//   3. k_agg1: inline-softmax gather-aggregate, 4 slots x 16 lanes, depth-3.
//   4. k_gemm2: LDS-free MFMA, fused scores2, 64B int8 node records.
//   5. k_agg2lsm: 1-line-per-edge aggregate + fused log_softmax.
// ---------------------------------------------------------------------------

#define LEAKY(e) ((e) >= 0.f ? (e) : 0.2f * (e))
#define GBLK 512
#define CHUNK 256

typedef unsigned short ushortT;
typedef unsigned int uintT;
typedef unsigned char ucharT;
typedef __attribute__((ext_vector_type(8))) short short8;
typedef __attribute__((ext_vector_type(4))) float float4v;

static __device__ __forceinline__ float bflo(uintT u) {
    return __uint_as_float(u << 16);
}
static __device__ __forceinline__ float bfhi(uintT u) {
    return __uint_as_float(u & 0xffff0000u);
}
static __device__ __forceinline__ ushortT f2bf(float f) {
    __hip_bfloat16 h = __float2bfloat16(f);   // RNE
    return *reinterpret_cast<ushortT*>(&h);
}
static __device__ __forceinline__ uintT pk(float a, float b) {
    return (uintT)f2bf(a) | ((uintT)f2bf(b) << 16);
}
static __device__ __forceinline__ float sb(uintT u, int k) {   // signed byte k
    return (float)((int)(u << (24 - 8 * k)) >> 24);
}

// ---------------- fused CSR build + weight prep (cooperative) --------------
__global__ __launch_bounds__(256) void k_csr(const int* __restrict__ ei, int E, int N,
                                             const float* __restrict__ W1,
                                             const float* __restrict__ W2,
                                             const float* __restrict__ a1s,
                                             const float* __restrict__ a1d,
                                             ushortT* __restrict__ W1t,
                                             ushortT* __restrict__ W2t,
                                             int* __restrict__ deg,
                                             int* __restrict__ rowptr,
                                             int* __restrict__ cursor,
                                             int* __restrict__ csr_src,
                                             int* __restrict__ part,
                                             int* __restrict__ tmp) {
    cg::grid_group grid = cg::this_grid();
    __shared__ int ws[4];
    __shared__ int s_carry;
    int t = threadIdx.x, b = blockIdx.x;
    int lane = t & 63, wv = t >> 6;
    int gtid = b * 256 + t, gsz = GBLK * 256;

    // ---- phase 0: zero deg + weight prep ----
    for (int i = gtid; i < N; i += gsz) deg[i] = 0;
    const int PREP = 128 * 256 + 48 * 256 + 2048;
    for (int i = gtid; i < PREP; i += gsz) {
        if (i < 128 * 256) {
            int k = i >> 8, s = i & 255;
            int c = ((s & 15) << 4) | (s >> 4);   // permuted col tiling
            W1t[s * 128 + k] = f2bf(W1[(size_t)k * 256 + c]);
        } else if (i < 128 * 256 + 48 * 256) {
            int q = i - 128 * 256;
            int k = q / 48, c = q - k * 48;
            W2t[c * 256 + k] = (c < 40) ? f2bf(W2[k * 40 + c]) : (ushortT)0;
        } else {
            int q = i - (128 * 256 + 48 * 256);
            int k = q >> 4, j = q & 15;
            int h = j & 7;
            const float* av = ((j < 8) ? a1s : a1d) + h * 32;
            const float* wr = W1 + (size_t)k * 256 + h * 32;
            float s = 0.f;
            #pragma unroll
            for (int c = 0; c < 32; ++c) s += wr[c] * av[c];
            W1t[(256 + j) * 128 + k] = f2bf(s);
        }
    }
    grid.sync();

    // ---- phase 1: degree histogram ----
    for (int e = gtid; e < E; e += gsz) atomicAdd(&deg[ei[E + e]], 1);
    grid.sync();

    // ---- phase 2a: per-chunk (256) inclusive scan of deg+1 ----
    int nch = (N + CHUNK - 1) / CHUNK;
    for (int c = b; c < nch; c += GBLK) {
        int i = c * CHUNK + t;
        int v = (i < N) ? (deg[i] + 1) : 0;   // +1 = self loop
        int incl = v;
        #pragma unroll
        for (int off = 1; off < 64; off <<= 1) {
            int u = __shfl_up(incl, off, 64);
            if (lane >= off) incl += u;
        }
        if (lane == 63) ws[wv] = incl;
        __syncthreads();
        int woff = 0;
        #pragma unroll
        for (int k = 0; k < 3; ++k) if (wv > k) woff += ws[k];
        incl += woff;
        if (i < N) tmp[i] = incl;
        if (t == 255) part[c] = incl;
        __syncthreads();
    }
    grid.sync();

    // ---- phase 2b: block 0 scans chunk totals with carry ----
    if (b == 0) {
        if (t == 0) s_carry = 0;
        __syncthreads();
        for (int base = 0; base < nch; base += 256) {
            int i = base + t;
            int v = (i < nch) ? part[i] : 0;
            int incl = v;
            #pragma unroll
            for (int off = 1; off < 64; off <<= 1) {
                int u = __shfl_up(incl, off, 64);
                if (lane >= off) incl += u;
            }
            if (lane == 63) ws[wv] = incl;
            __syncthreads();
            int woff = 0;
            #pragma unroll
            for (int k = 0; k < 3; ++k) if (wv > k) woff += ws[k];
            incl += woff;
            int tot = ws[0] + ws[1] + ws[2] + ws[3];
            int c0 = s_carry;
            __syncthreads();
            if (i < nch) part[i] = c0 + incl;
            if (t == 0) s_carry = c0 + tot;
            __syncthreads();
        }
    }
    grid.sync();

    // ---- phase 2c: rowptr / cursor / self-loop placement ----
    for (int i = gtid; i < N; i += gsz) {
        int c = i >> 8;   // CHUNK = 256
        int off = c ? part[c - 1] : 0;
        int incl = tmp[i] + off;
        rowptr[i + 1] = incl;
        int start = incl - (deg[i] + 1);
        csr_src[start] = i;          // self loop pre-placed
        cursor[i] = start + 1;
        if (i == 0) rowptr[0] = 0;
    }
    grid.sync();

    // ---- phase 3/4: dst-ranged scatter (write window ~3.4 MB per pass) ----
    int half = (N + 1) / 2;
    for (int e = gtid; e < E; e += gsz) {
        int dst = ei[E + e];
        if (dst < half) {
            int pos = atomicAdd(&cursor[dst], 1);
            csr_src[pos] = ei[e];
        }
    }
    grid.sync();
    for (int e = gtid; e < E; e += gsz) {
        int dst = ei[E + e];
        if (dst >= half) {
            int pos = atomicAdd(&cursor[dst], 1);
            csr_src[pos] = ei[e];
        }
    }
}

// ---------------- GEMM1: x[M,128] @ W1 -> int8 h1i + packed spk + s1d ------
__global__ __launch_bounds__(256) void k_gemm1(const float* __restrict__ A,
                                               const ushortT* __restrict__ Bt,
                                               ucharT* __restrict__ h1i,
                                               uintT* __restrict__ spk,
                                               float* __restrict__ s1d, int M) {
    int lane = threadIdx.x & 63, wave = threadIdx.x >> 6;
    int slab = blockIdx.x * 4 + wave;
    int r0 = slab * 16;
    if (r0 >= M) return;
    int n = lane & 15, q = lane >> 4;
    const float* arow = A + (size_t)(r0 + n) * 128 + q * 8;
    short8 af[4];
    #pragma unroll
    for (int s = 0; s < 4; ++s) {
        float4 v0 = *(const float4*)(arow + s * 32);
        float4 v1 = *(const float4*)(arow + s * 32 + 4);
        short8 a;
        a[0] = (short)f2bf(v0.x); a[1] = (short)f2bf(v0.y);
        a[2] = (short)f2bf(v0.z); a[3] = (short)f2bf(v0.w);
        a[4] = (short)f2bf(v1.x); a[5] = (short)f2bf(v1.y);
        a[6] = (short)f2bf(v1.z); a[7] = (short)f2bf(v1.w);
        af[s] = a;
    }
    float4v acc[17];
    #pragma unroll
    for (int j = 0; j < 17; ++j) acc[j] = (float4v){0.f, 0.f, 0.f, 0.f};
    #pragma unroll
    for (int s = 0; s < 4; ++s) {
        #pragma unroll
        for (int j = 0; j < 17; ++j) {
            short8 b = *(const short8*)(Bt + (size_t)(j * 16 + n) * 128 + s * 32 + q * 8);
            acc[j] = __builtin_amdgcn_mfma_f32_16x16x32_bf16(af[s], b, acc[j], 0, 0, 0);
        }
    }
    // acc[j][r] = value for row (r0+q*4+r), ORIGINAL col (16n + j)
    float am[4];
    #pragma unroll
    for (int r = 0; r < 4; ++r) {
        float m = 0.f;
        #pragma unroll
        for (int j = 0; j < 16; ++j) m = fmaxf(m, fabsf(acc[j][r]));
        am[r] = m;
    }
    #pragma unroll
    for (int off = 1; off < 16; off <<= 1) {
        #pragma unroll
        for (int r = 0; r < 4; ++r) am[r] = fmaxf(am[r], __shfl_xor(am[r], off, 64));
    }
    #pragma unroll
    for (int r = 0; r < 4; ++r) {
        int row = r0 + q * 4 + r;
        float m = am[r];
        float si = (m > 0.f) ? 127.f / m : 0.f;
        uintT wd[4];
        #pragma unroll
        for (int wq = 0; wq < 4; ++wq) {
            uintT p4 = 0;
            #pragma unroll
            for (int b = 0; b < 4; ++b) {
                int j = wq * 4 + b;
                int qv = (int)rintf(acc[j][r] * si);
                p4 |= ((uintT)(qv & 0xff)) << (8 * b);
            }
            wd[wq] = p4;
        }
        uint4 o = make_uint4(wd[0], wd[1], wd[2], wd[3]);
        *(uint4*)(h1i + (size_t)row * 256 + n * 16) = o;
        float vv = acc[16][r];
        if (n < 8) spk[(size_t)row * 8 + n] = pk(vv, m * (1.f / 127.f));
        else       s1d[(size_t)row * 8 + (n - 8)] = vv;
    }
}

// ---------------- layer-1 aggregation: 4 slots x 16 lanes x uint4, depth-3 -
__global__ __launch_bounds__(256) void k_agg1(const ucharT* __restrict__ h1i,
                                              const uintT* __restrict__ spk,
                                              const float* __restrict__ sdst,
                                              const int* __restrict__ rowptr,
                                              const int* __restrict__ csr_src,
                                              const float* __restrict__ b1,
                                              ushortT* __restrict__ out1, int N) {
    int lane = threadIdx.x & 63;
    int wid = threadIdx.x >> 6;
    int n = blockIdx.x * 4 + wid;
    if (n >= N) return;
    int slot = lane >> 4;        // 4 edge slots
    int cl = lane & 15;          // 16 channels each (int8)
    int head = cl >> 1;
    int beg = rowptr[n], end = rowptr[n + 1];
    float sdn = sdst[(size_t)n * 8 + head];
    const ucharT* hb = h1i + cl * 16;
    float acc[16];
    #pragma unroll
    for (int k = 0; k < 16; ++k) acc[k] = 0.f;
    float l = 0.f;
    int i0 = beg + slot;
    uintT sp0 = 0u, sp1 = 0u, sp2 = 0u;
    uint4 v0 = make_uint4(0u, 0u, 0u, 0u), v1 = v0, v2 = v0;
    if (i0 < end) {
        int s = csr_src[i0];
        sp0 = spk[(size_t)s * 8 + head];
        v0 = *(const uint4*)(hb + (size_t)s * 256);
    }
    if (i0 + 4 < end) {
        int s = csr_src[i0 + 4];
        sp1 = spk[(size_t)s * 8 + head];
        v1 = *(const uint4*)(hb + (size_t)s * 256);
    }
    if (i0 + 8 < end) {
        int s = csr_src[i0 + 8];
        sp2 = spk[(size_t)s * 8 + head];
        v2 = *(const uint4*)(hb + (size_t)s * 256);
    }
    for (int idx = i0; idx < end; idx += 4) {
        uintT sp = sp0; uint4 v = v0;
        sp0 = sp1; v0 = v1;
        sp1 = sp2; v1 = v2;
        int ip = idx + 12;
        if (ip < end) {
            int s = csr_src[ip];
            sp2 = spk[(size_t)s * 8 + head];
            v2 = *(const uint4*)(hb + (size_t)s * 256);
        }
        float p = __expf(LEAKY(bflo(sp) + sdn));
        l += p;
        float ps = p * bfhi(sp);
        acc[0]  += ps * sb(v.x, 0); acc[1]  += ps * sb(v.x, 1);
        acc[2]  += ps * sb(v.x, 2); acc[3]  += ps * sb(v.x, 3);
        acc[4]  += ps * sb(v.y, 0); acc[5]  += ps * sb(v.y, 1);
        acc[6]  += ps * sb(v.y, 2); acc[7]  += ps * sb(v.y, 3);
        acc[8]  += ps * sb(v.z, 0); acc[9]  += ps * sb(v.z, 1);
        acc[10] += ps * sb(v.z, 2); acc[11] += ps * sb(v.z, 3);
        acc[12] += ps * sb(v.w, 0); acc[13] += ps * sb(v.w, 1);
        acc[14] += ps * sb(v.w, 2); acc[15] += ps * sb(v.w, 3);
    }
    #pragma unroll
    for (int k = 0; k < 16; ++k) {
        acc[k] += __shfl_xor(acc[k], 16, 64);
        acc[k] += __shfl_xor(acc[k], 32, 64);
    }
    l += __shfl_xor(l, 16, 64);
    l += __shfl_xor(l, 32, 64);
    if (slot == 0) {
        float inv = 1.f / l;
        const float* bb = b1 + cl * 16;
        float r[16];
        #pragma unroll
        for (int k = 0; k < 16; ++k) r[k] = fmaxf(acc[k] * inv + bb[k], 0.f);
        uint4 oA, oB;
        oA.x = pk(r[0], r[1]);   oA.y = pk(r[2], r[3]);
        oA.z = pk(r[4], r[5]);   oA.w = pk(r[6], r[7]);
        oB.x = pk(r[8], r[9]);   oB.y = pk(r[10], r[11]);
        oB.z = pk(r[12], r[13]); oB.w = pk(r[14], r[15]);
        ushortT* orow = out1 + (size_t)n * 256 + cl * 16;
        *(uint4*)(orow) = oA;
        *(uint4*)(orow + 8) = oB;
    }
}

// ---------------- GEMM2: out1b @ W2 -> 64B int8 node records + s2d ---------
// record: [0..39] int8 vals, [40..47] pad, [48] score_src f32, [52] scale f32
__global__ __launch_bounds__(256) void k_gemm2(const ushortT* __restrict__ X,
                                               const ushortT* __restrict__ Bt,
                                               const float* __restrict__ a2s,
                                               const float* __restrict__ a2d,
                                               ucharT* __restrict__ h2r,
                                               float* __restrict__ s2d, int M) {
    int lane = threadIdx.x & 63, wave = threadIdx.x >> 6;
    int slab = blockIdx.x * 4 + wave;
    int r0 = slab * 16;
    if (r0 >= M) return;
    int n = lane & 15, q = lane >> 4;
    const ushortT* xrow = X + (size_t)(r0 + n) * 256 + q * 8;
    float4v acc[3];
    #pragma unroll
    for (int j = 0; j < 3; ++j) acc[j] = (float4v){0.f, 0.f, 0.f, 0.f};
    #pragma unroll
    for (int s = 0; s < 8; ++s) {
        short8 a = *(const short8*)(xrow + s * 32);
        #pragma unroll
        for (int j = 0; j < 3; ++j) {
            short8 b = *(const short8*)(Bt + (size_t)(j * 16 + n) * 256 + s * 32 + q * 8);
            acc[j] = __builtin_amdgcn_mfma_f32_16x16x32_bf16(a, b, acc[j], 0, 0, 0);
        }
    }
    float asv[3], adv[3];
    #pragma unroll
    for (int j = 0; j < 3; ++j) {
        int col = j * 16 + n;
        asv[j] = (col < 40) ? a2s[col] : 0.f;
        adv[j] = (col < 40) ? a2d[col] : 0.f;
    }
    float us[4], ud[4], am[4];
    #pragma unroll
    for (int r = 0; r < 4; ++r) {
        us[r] = acc[0][r] * asv[0] + acc[1][r] * asv[1] + acc[2][r] * asv[2];
        ud[r] = acc[0][r] * adv[0] + acc[1][r] * adv[1] + acc[2][r] * adv[2];
        am[r] = fmaxf(fmaxf(fabsf(acc[0][r]), fabsf(acc[1][r])), fabsf(acc[2][r]));
    }
    #pragma unroll
    for (int off = 1; off < 16; off <<= 1) {
        #pragma unroll
        for (int r = 0; r < 4; ++r) {
            us[r] += __shfl_xor(us[r], off, 64);
            ud[r] += __shfl_xor(ud[r], off, 64);
            am[r] = fmaxf(am[r], __shfl_xor(am[r], off, 64));
        }
    }
    #pragma unroll
    for (int r = 0; r < 4; ++r) {
        int row = r0 + q * 4 + r;
        ucharT* rec = h2r + (size_t)row * 64;
        float m = am[r];
        float si = (m > 0.f) ? 127.f / m : 0.f;
        #pragma unroll
        for (int j = 0; j < 3; ++j) {
            int col = j * 16 + n;
            if (col < 40) {
                int qv = (int)rintf(acc[j][r] * si);
                rec[col] = (ucharT)(qv & 0xff);
            }
        }
        if (n == 0) {
            *(float2*)(rec + 48) = make_float2(us[r], m * (1.f / 127.f));
            s2d[row] = ud[r];
        }
    }
}

// ---------------- layer-2 aggregation + log_softmax (1-line records) -------
__global__ __launch_bounds__(256) void k_agg2lsm(const ucharT* __restrict__ h2r,
                                                 const float* __restrict__ sd,
                                                 const int* __restrict__ rowptr,
                                                 const int* __restrict__ csr_src,
                                                 const float* __restrict__ b2,
                                                 float* __restrict__ out, int N) {
    int lane = threadIdx.x & 63;
    int wid = threadIdx.x >> 6;
    int n = blockIdx.x * 4 + wid;
    if (n >= N) return;
    int el = lane / 10;
    int cl = lane - el * 10;
    int beg = rowptr[n], end = rowptr[n + 1];
    float sdn = sd[n];
    float a0 = 0.f, a1 = 0.f, a2 = 0.f, a3 = 0.f, l = 0.f;
    if (el < 6) {
        int ia = beg + el;
        float2 sp0 = make_float2(0.f, 0.f), sp1 = sp0, sp2 = sp0;
        uintT v0 = 0u, v1 = 0u, v2 = 0u;
        if (ia < end) {
            const ucharT* rec = h2r + (size_t)csr_src[ia] * 64;
            v0 = *(const uintT*)(rec + cl * 4);
            sp0 = *(const float2*)(rec + 48);
        }
        if (ia + 6 < end) {
            const ucharT* rec = h2r + (size_t)csr_src[ia + 6] * 64;
            v1 = *(const uintT*)(rec + cl * 4);
            sp1 = *(const float2*)(rec + 48);
        }
        if (ia + 12 < end) {
            const ucharT* rec = h2r + (size_t)csr_src[ia + 12] * 64;
            v2 = *(const uintT*)(rec + cl * 4);
            sp2 = *(const float2*)(rec + 48);
        }
        for (int idx = ia; idx < end; idx += 6) {
            float2 sp = sp0; uintT v = v0;
            sp0 = sp1; v0 = v1;
            sp1 = sp2; v1 = v2;
            int i3 = idx + 18;
            if (i3 < end) {
                const ucharT* rec = h2r + (size_t)csr_src[i3] * 64;
                v2 = *(const uintT*)(rec + cl * 4);
                sp2 = *(const float2*)(rec + 48);
            }
            float p = __expf(LEAKY(sp.x + sdn));
            l += p;
            float ps = p * sp.y;
            a0 += ps * sb(v, 0); a1 += ps * sb(v, 1);
            a2 += ps * sb(v, 2); a3 += ps * sb(v, 3);
        }
    }
    // reduce the 6 slots into lanes 0..9
    float t0 = 0.f, t1 = 0.f, t2 = 0.f, t3 = 0.f, lt = 0.f;
    #pragma unroll
    for (int k = 0; k < 6; ++k) {
        int sl = cl + 10 * k;
        t0 += __shfl(a0, sl, 64);
        t1 += __shfl(a1, sl, 64);
        t2 += __shfl(a2, sl, 64);
        t3 += __shfl(a3, sl, 64);
        if (cl == 0) lt += __shfl(l, sl, 64);
    }
    lt = __shfl(lt, 0, 64);
    float inv = 1.f / lt;
    float o0 = t0 * inv + b2[cl * 4 + 0];
    float o1 = t1 * inv + b2[cl * 4 + 1];
    float o2 = t2 * inv + b2[cl * 4 + 2];
    float o3 = t3 * inv + b2[cl * 4 + 3];
    float lm = (lane < 10) ? fmaxf(fmaxf(o0, o1), fmaxf(o2, o3)) : -INFINITY;
    #pragma unroll
    for (int off = 32; off; off >>= 1) lm = fmaxf(lm, __shfl_xor(lm, off, 64));
    float le = (lane < 10)
        ? __expf(o0 - lm) + __expf(o1 - lm) + __expf(o2 - lm) + __expf(o3 - lm)
        : 0.f;
    #pragma unroll
    for (int off = 32; off; off >>= 1) le += __shfl_xor(le, off, 64);
    float ls = lm + logf(le);
    if (lane < 10) {
        float4 w = make_float4(o0 - ls, o1 - ls, o2 - ls, o3 - ls);
        *(float4*)(out + (size_t)n * 40 + cl * 4) = w;
    }
}

// ---------------------------------------------------------------------------
extern "C" void kernel_launch(void* const* d_in, const int* in_sizes, int n_in,
                              void* d_out, int out_size, void* d_ws, size_t ws_size,
                              hipStream_t stream) {
    const float* x   = (const float*)d_in[0];
    const int*   ei  = (const int*)d_in[1];
    const float* W1  = (const float*)d_in[2];
    const float* a1s = (const float*)d_in[3];
    const float* a1d = (const float*)d_in[4];
    const float* b1  = (const float*)d_in[5];
    const float* W2  = (const float*)d_in[6];
    const float* a2s = (const float*)d_in[7];
    const float* a2d = (const float*)d_in[8];
    const float* b2  = (const float*)d_in[9];
    float* out = (float*)d_out;

    int N = in_sizes[0] / 128;   // 100000
    int E = in_sizes[1] / 2;     // 1600000
    const int ET = E + N;

    // ---- workspace layout ----
    char* w = (char*)d_ws;
    ucharT* h1i = (ucharT*)w;                             // N*256 int8 (25.6 MB)
    uintT* spk  = (uintT*)(w + (size_t)N * 256);          // N*8 packed bf16 pairs
    ushortT* out1b = (ushortT*)(w + (size_t)N * 256 + (size_t)N * 32);  // N*256 bf16
    float* s1d  = (float*)(out1b + (size_t)N * 256);      // N*8
    int* i_deg = (int*)(s1d + (size_t)N * 8);
    int* i_row = i_deg + (N + 16);
    int* i_cur = i_row + (N + 16);
    int* i_tmp = i_cur + (N + 16);
    int* i_par = i_tmp + (N + 16);
    int* i_csr = i_par + 2048;                            // ET ints
    ushortT* W1t = (ushortT*)(i_csr + ET);                // 272*128 bf16
    ushortT* W2t = W1t + 272 * 128;                       // 48*256 bf16
    // layer-2 overlays h1i (dead after k_agg1)
    ucharT* h2r = (ucharT*)w;                             // N*64 records (6.4 MB)
    float* s2d  = (float*)(w + (size_t)N * 64);           // N

    const int nb4 = (N + 3) / 4;
    const int nbG = (N / 16 + 3) / 4;   // gemm blocks (4 waves x 16 rows)

    // ---- 1. fused CSR build + weight prep (cooperative) ----
    {
        void* args[] = {&ei, &E, &N, &W1, &W2, &a1s, &a1d, &W1t, &W2t,
                        &i_deg, &i_row, &i_cur, &i_csr, &i_par, &i_tmp};
        hipLaunchCooperativeKernel((void*)k_csr, dim3(GBLK), dim3(256),
                                   args, 0, stream);
    }

    // ---- 2-3. layer 1 ----
    k_gemm1<<<nbG, 256, 0, stream>>>(x, W1t, h1i, spk, s1d, N);
    k_agg1<<<nb4, 256, 0, stream>>>(h1i, spk, s1d, i_row, i_csr, b1, out1b, N);

    // ---- 4-5. layer 2 ----
    k_gemm2<<<nbG, 256, 0, stream>>>(out1b, W2t, a2s, a2d, h2r, s2d, N);
    k_agg2lsm<<<nb4, 256, 0, stream>>>(h2r, s2d, i_row, i_csr, b2, out, N);
}